// Round 8
// baseline (44.680 us; speedup 1.0000x reference)
//
#include <hip/hip_runtime.h>
#include <hip/hip_bf16.h>

#define NPATCH 196

typedef float f2 __attribute__((ext_vector_type(2)));

// ---- setup: ONE block, 256 threads (verbatim round-6, verified absmax 0.0).
// Computes C[(a*9+q)*4+w] so that feat_w = sum_{a,q} C[(a*9+q)*4+w]*m01[a]*m23[q],
// a = 3*alpha0+alpha1 (wires 0,1), q = 3*alpha2+alpha3 (wires 2,3),
// alpha: 0->1, 1->cos(angle), 2->sin(angle).
__global__ __launch_bounds__(256) void quanv_setup(const float* __restrict__ P,
                                                   float* __restrict__ C) {
  __shared__ float gc[24], gs[24];
  __shared__ float Ur[8][2][2], Ui[8][2][2];  // merged RZ*RY*RX per (d,w)
  __shared__ float Sr[2][16][16], Si[2][16][16];
  __shared__ float A[4][16][16];
  __shared__ float B0[4][3][8][8];
  __shared__ float B1[4][3][3][4][4];
  __shared__ float B2[4][3][3][3][2][2];
  const int tid = threadIdx.x;
  const int row = tid >> 4, col = tid & 15;

  if (tid < 24) {  // P laid out [(d*4+w)*3+g]; |theta/2| small -> __sincosf fine
    float s, c;
    __sincosf(0.5f * P[tid], &s, &c);
    gc[tid] = c; gs[tid] = s;
  }
  Sr[0][row][col] = (row == col) ? 1.0f : 0.0f;
  Si[0][row][col] = 0.0f;
  __syncthreads();

  if (tid < 8) {  // U = RZ(t3)*RY(t2)*RX(t1), 2x2 complex
    const int base = tid * 3;
    const float c1 = gc[base], s1 = gs[base];
    const float c2 = gc[base + 1], s2 = gs[base + 1];
    const float c3 = gc[base + 2], s3 = gs[base + 2];
    const float m00r = c2 * c1, m00i = s2 * s1;
    const float m01r = -s2 * c1, m01i = -c2 * s1;
    const float m10r = s2 * c1, m10i = -c2 * s1;
    const float m11r = c2 * c1, m11i = -s2 * s1;
    Ur[tid][0][0] = c3 * m00r + s3 * m00i;  Ui[tid][0][0] = c3 * m00i - s3 * m00r;
    Ur[tid][0][1] = c3 * m01r + s3 * m01i;  Ui[tid][0][1] = c3 * m01i - s3 * m01r;
    Ur[tid][1][0] = c3 * m10r - s3 * m10i;  Ui[tid][1][0] = c3 * m10i + s3 * m10r;
    Ur[tid][1][1] = c3 * m11r - s3 * m11i;  Ui[tid][1][1] = c3 * m11i + s3 * m11r;
  }
  __syncthreads();

  int cur = 0;
  for (int d = 0; d < 2; ++d) {
    for (int w = 0; w < 4; ++w) {
      const int gi = d * 4 + w;
      const int m = 8 >> w;
      const int bit = (row & m) ? 1 : 0;
      const int par = row ^ m;
      const int r0 = bit ? par : row, r1 = bit ? row : par;
      const float a_r = Sr[cur][r0][col], a_i = Si[cur][r0][col];
      const float b_r = Sr[cur][r1][col], b_i = Si[cur][r1][col];
      const float u0r = Ur[gi][bit][0], u0i = Ui[gi][bit][0];
      const float u1r = Ur[gi][bit][1], u1i = Ui[gi][bit][1];
      const float rn = u0r * a_r - u0i * a_i + u1r * b_r - u1i * b_i;
      const float in_ = u0r * a_i + u0i * a_r + u1r * b_i + u1i * b_r;
      Sr[cur ^ 1][row][col] = rn;
      Si[cur ^ 1][row][col] = in_;
      cur ^= 1;
      __syncthreads();
    }
    if (d == 0) {  // CNOT ring as one permutation: new[k] = old[chain(k)]
      int k = row;
      k ^= (k & 1) ? 8 : 0;
      k ^= (k & 2) ? 1 : 0;
      k ^= (k & 4) ? 2 : 0;
      k ^= (k & 8) ? 4 : 0;
      const float pr_ = Sr[cur][k][col], pi_ = Si[cur][k][col];
      Sr[cur ^ 1][row][col] = pr_;
      Si[cur ^ 1][row][col] = pi_;
      cur ^= 1;
      __syncthreads();
    }
  }

  {  // A_w[i][j]; second CNOT perm folded into row index
    const int i = row, j = col;
    float s0 = 0, s1 = 0, s2 = 0, s3 = 0;
#pragma unroll
    for (int k = 0; k < 16; ++k) {
      int gk = k;
      gk ^= (gk & 1) ? 8 : 0;
      gk ^= (gk & 2) ? 1 : 0;
      gk ^= (gk & 4) ? 2 : 0;
      gk ^= (gk & 8) ? 4 : 0;
      const float pr = Sr[cur][gk][i] * Sr[cur][gk][j] + Si[cur][gk][i] * Si[cur][gk][j];
      s0 += (k & 8) ? -pr : pr;
      s1 += (k & 4) ? -pr : pr;
      s2 += (k & 2) ? -pr : pr;
      s3 += (k & 1) ? -pr : pr;
    }
    A[0][i][j] = s0; A[1][i][j] = s1; A[2][i][j] = s2; A[3][i][j] = s3;
  }
  __syncthreads();

  // wire-factorized basis transform: a=0: .5(X00+X11); a=1: .5(X00-X11); a=2: .5(X01+X10)
  {  // wire 0
    const int w = tid >> 6, ip = (tid >> 3) & 7, jp = tid & 7;
    const float a00 = A[w][ip][jp],     a11 = A[w][ip + 8][jp + 8];
    const float a01 = A[w][ip][jp + 8], a10 = A[w][ip + 8][jp];
    B0[w][0][ip][jp] = 0.5f * (a00 + a11);
    B0[w][1][ip][jp] = 0.5f * (a00 - a11);
    B0[w][2][ip][jp] = 0.5f * (a01 + a10);
  }
  __syncthreads();
  if (tid < 192) {  // wire 1
    const int w = tid / 48, a0 = (tid / 16) % 3, ii = (tid >> 2) & 3, jj = tid & 3;
    const float a00 = B0[w][a0][ii][jj],     a11 = B0[w][a0][ii + 4][jj + 4];
    const float a01 = B0[w][a0][ii][jj + 4], a10 = B0[w][a0][ii + 4][jj];
    B1[w][a0][0][ii][jj] = 0.5f * (a00 + a11);
    B1[w][a0][1][ii][jj] = 0.5f * (a00 - a11);
    B1[w][a0][2][ii][jj] = 0.5f * (a01 + a10);
  }
  __syncthreads();
  if (tid < 144) {  // wire 2
    const int w = tid / 36, a0 = (tid / 12) % 3, a1 = (tid / 4) % 3;
    const int i3 = (tid >> 1) & 1, j3 = tid & 1;
    const float a00 = B1[w][a0][a1][i3][j3],     a11 = B1[w][a0][a1][i3 + 2][j3 + 2];
    const float a01 = B1[w][a0][a1][i3][j3 + 2], a10 = B1[w][a0][a1][i3 + 2][j3];
    B2[w][a0][a1][0][i3][j3] = 0.5f * (a00 + a11);
    B2[w][a0][a1][1][i3][j3] = 0.5f * (a00 - a11);
    B2[w][a0][a1][2][i3][j3] = 0.5f * (a01 + a10);
  }
  __syncthreads();
  if (tid < 108) {  // wire 3 -> C
    const int w = tid / 27, r = tid % 27;
    const int a0 = r / 9, a1 = (r / 3) % 3, a2 = r % 3;
    const float a00 = B2[w][a0][a1][a2][0][0], a11 = B2[w][a0][a1][a2][1][1];
    const float a01 = B2[w][a0][a1][a2][0][1], a10 = B2[w][a0][a1][a2][1][0];
    const int base = (3 * a0 + a1) * 9 + 3 * a2;
    C[(base + 0) * 4 + w] = 0.5f * (a00 + a11);
    C[(base + 1) * 4 + w] = 0.5f * (a00 - a11);
    C[(base + 2) * 4 + w] = 0.5f * (a01 + a10);
  }
}

// ---- main: ONE WAVE PER IMAGE. Block = 4 waves = 4 images. Zero barriers
// after C staging; in-wave butterfly reduction; no idle 4th wave.
__global__ __launch_bounds__(256) void quanv_main(const float* __restrict__ x,
                                                  const float* __restrict__ W,
                                                  const float* __restrict__ bias,
                                                  const float* __restrict__ C,
                                                  float* __restrict__ out,
                                                  int B) {
  __shared__ float4 Cl[81];
  const int tid = threadIdx.x;
  if (tid < 81) Cl[tid] = reinterpret_cast<const float4*>(C)[tid];
  __syncthreads();

  const int wid = tid >> 6, lane = tid & 63;
  const int b = blockIdx.x * 4 + wid;
  if (b >= B) return;
  const float* xb = x + b * 784;

  float lg[10];
#pragma unroll
  for (int k = 0; k < 10; ++k) lg[k] = 0.0f;

#pragma unroll
  for (int t = 0; t < 4; ++t) {
    const int p = lane + 64 * t;
    if (t < 3 || p < NPATCH) {
      const int pi = p / 14, pj = p - pi * 14;
      const float* px = xb + pi * 56 + pj * 2;
      const float2 r0 = *reinterpret_cast<const float2*>(px);
      const float2 r1 = *reinterpret_cast<const float2*>(px + 28);
      float c0, s0, c1, s1, c2, s2, c3, s3;
      __sincosf(r0.x, &s0, &c0);
      __sincosf(r0.y, &s1, &c1);
      __sincosf(r1.x, &s2, &c2);
      __sincosf(r1.y, &s3, &c3);
      const float m01s[9] = {1.0f, c1, s1, c0, c0 * c1, c0 * s1, s0, s0 * c1, s0 * s1};
      const float m23s[9] = {1.0f, c3, s3, c2, c2 * c3, c2 * s3, s2, s2 * c3, s2 * s3};
      f2 m23b[9];
#pragma unroll
      for (int q = 0; q < 9; ++q) m23b[q] = (f2){m23s[q], m23s[q]};

      f2 f01 = {0.0f, 0.0f}, f23 = {0.0f, 0.0f};
#pragma unroll
      for (int a = 0; a < 9; ++a) {
        f2 t01 = {0.0f, 0.0f}, t23 = {0.0f, 0.0f};
#pragma unroll
        for (int q = 0; q < 9; ++q) {
          const float4 cc = Cl[a * 9 + q];     // wave-uniform LDS broadcast
          t01 += (f2){cc.x, cc.y} * m23b[q];   // v_pk_fma_f32
          t23 += (f2){cc.z, cc.w} * m23b[q];
        }
        f01 += t01 * m01s[a];
        f23 += t23 * m01s[a];
      }

      const float* Wp = W + p * 4;  // feature index = p*4 + w
#pragma unroll
      for (int k = 0; k < 10; ++k) {
        const float4 wv = *reinterpret_cast<const float4*>(Wp + k * 784);
        lg[k] += f01.x * wv.x + f01.y * wv.y + f23.x * wv.z + f23.y * wv.w;
      }
    }
  }

  // full-wave butterfly: every lane ends with all-196-patch sums
#pragma unroll
  for (int k = 0; k < 10; ++k) {
    float v = lg[k];
    v += __shfl_xor(v, 1);
    v += __shfl_xor(v, 2);
    v += __shfl_xor(v, 4);
    v += __shfl_xor(v, 8);
    v += __shfl_xor(v, 16);
    v += __shfl_xor(v, 32);
    lg[k] = v;
  }
#pragma unroll
  for (int k = 0; k < 10; ++k) lg[k] += bias[k];

  // log_softmax computed redundantly in all lanes (registers only)
  float m = lg[0];
#pragma unroll
  for (int k = 1; k < 10; ++k) m = fmaxf(m, lg[k]);
  float se = 0.0f;
#pragma unroll
  for (int k = 0; k < 10; ++k) se += expf(lg[k] - m);
  const float sn = m + logf(se);

  if (lane < 10) {
    float v = lg[0];
#pragma unroll
    for (int k = 1; k < 10; ++k) v = (lane == k) ? lg[k] : v;
    out[b * 10 + lane] = v - sn;
  }
}

extern "C" void kernel_launch(void* const* d_in, const int* in_sizes, int n_in,
                              void* d_out, int out_size, void* d_ws, size_t ws_size,
                              hipStream_t stream) {
  const float* x = (const float*)d_in[0];     // (B,1,28,28) f32
  const float* P = (const float*)d_in[1];     // (2,4,3) f32
  const float* W = (const float*)d_in[2];     // (10,784) f32
  const float* bias = (const float*)d_in[3];  // (10,) f32
  float* out = (float*)d_out;                 // (B,10) f32
  float* C = (float*)d_ws;                    // 324 floats scratch
  const int B = out_size / 10;

  quanv_setup<<<1, 256, 0, stream>>>(P, C);
  quanv_main<<<(B + 3) / 4, 256, 0, stream>>>(x, W, bias, C, out, B);
}

// Round 9
// 33.037 us; speedup vs baseline: 1.3524x; 1.3524x over previous
//
#include <hip/hip_runtime.h>
#include <hip/hip_bf16.h>

#define NPATCH 196

typedef float f2 __attribute__((ext_vector_type(2)));

// ---- setup: ONE block, 256 threads (verbatim, verified absmax 0.0).
// Computes C[(a*9+q)*4+w] so that feat_w = sum_{a,q} C[(a*9+q)*4+w]*m01[a]*m23[q],
// a = 3*alpha0+alpha1 (wires 0,1), q = 3*alpha2+alpha3 (wires 2,3),
// alpha: 0->1, 1->cos(angle), 2->sin(angle).
__global__ __launch_bounds__(256) void quanv_setup(const float* __restrict__ P,
                                                   float* __restrict__ C) {
  __shared__ float gc[24], gs[24];
  __shared__ float Ur[8][2][2], Ui[8][2][2];  // merged RZ*RY*RX per (d,w)
  __shared__ float Sr[2][16][16], Si[2][16][16];
  __shared__ float A[4][16][16];
  __shared__ float B0[4][3][8][8];
  __shared__ float B1[4][3][3][4][4];
  __shared__ float B2[4][3][3][3][2][2];
  const int tid = threadIdx.x;
  const int row = tid >> 4, col = tid & 15;

  if (tid < 24) {  // P laid out [(d*4+w)*3+g]
    float s, c;
    __sincosf(0.5f * P[tid], &s, &c);
    gc[tid] = c; gs[tid] = s;
  }
  Sr[0][row][col] = (row == col) ? 1.0f : 0.0f;
  Si[0][row][col] = 0.0f;
  __syncthreads();

  if (tid < 8) {  // U = RZ(t3)*RY(t2)*RX(t1), 2x2 complex
    const int base = tid * 3;
    const float c1 = gc[base], s1 = gs[base];
    const float c2 = gc[base + 1], s2 = gs[base + 1];
    const float c3 = gc[base + 2], s3 = gs[base + 2];
    const float m00r = c2 * c1, m00i = s2 * s1;
    const float m01r = -s2 * c1, m01i = -c2 * s1;
    const float m10r = s2 * c1, m10i = -c2 * s1;
    const float m11r = c2 * c1, m11i = -s2 * s1;
    Ur[tid][0][0] = c3 * m00r + s3 * m00i;  Ui[tid][0][0] = c3 * m00i - s3 * m00r;
    Ur[tid][0][1] = c3 * m01r + s3 * m01i;  Ui[tid][0][1] = c3 * m01i - s3 * m01r;
    Ur[tid][1][0] = c3 * m10r - s3 * m10i;  Ui[tid][1][0] = c3 * m10i + s3 * m10r;
    Ur[tid][1][1] = c3 * m11r - s3 * m11i;  Ui[tid][1][1] = c3 * m11i + s3 * m11r;
  }
  __syncthreads();

  int cur = 0;
  for (int d = 0; d < 2; ++d) {
    for (int w = 0; w < 4; ++w) {
      const int gi = d * 4 + w;
      const int m = 8 >> w;
      const int bit = (row & m) ? 1 : 0;
      const int par = row ^ m;
      const int r0 = bit ? par : row, r1 = bit ? row : par;
      const float a_r = Sr[cur][r0][col], a_i = Si[cur][r0][col];
      const float b_r = Sr[cur][r1][col], b_i = Si[cur][r1][col];
      const float u0r = Ur[gi][bit][0], u0i = Ui[gi][bit][0];
      const float u1r = Ur[gi][bit][1], u1i = Ui[gi][bit][1];
      const float rn = u0r * a_r - u0i * a_i + u1r * b_r - u1i * b_i;
      const float in_ = u0r * a_i + u0i * a_r + u1r * b_i + u1i * b_r;
      Sr[cur ^ 1][row][col] = rn;
      Si[cur ^ 1][row][col] = in_;
      cur ^= 1;
      __syncthreads();
    }
    if (d == 0) {  // CNOT ring as one permutation: new[k] = old[chain(k)]
      int k = row;
      k ^= (k & 1) ? 8 : 0;
      k ^= (k & 2) ? 1 : 0;
      k ^= (k & 4) ? 2 : 0;
      k ^= (k & 8) ? 4 : 0;
      const float pr_ = Sr[cur][k][col], pi_ = Si[cur][k][col];
      Sr[cur ^ 1][row][col] = pr_;
      Si[cur ^ 1][row][col] = pi_;
      cur ^= 1;
      __syncthreads();
    }
  }

  {  // A_w[i][j]; second CNOT perm folded into row index
    const int i = row, j = col;
    float s0 = 0, s1 = 0, s2 = 0, s3 = 0;
#pragma unroll
    for (int k = 0; k < 16; ++k) {
      int gk = k;
      gk ^= (gk & 1) ? 8 : 0;
      gk ^= (gk & 2) ? 1 : 0;
      gk ^= (gk & 4) ? 2 : 0;
      gk ^= (gk & 8) ? 4 : 0;
      const float pr = Sr[cur][gk][i] * Sr[cur][gk][j] + Si[cur][gk][i] * Si[cur][gk][j];
      s0 += (k & 8) ? -pr : pr;
      s1 += (k & 4) ? -pr : pr;
      s2 += (k & 2) ? -pr : pr;
      s3 += (k & 1) ? -pr : pr;
    }
    A[0][i][j] = s0; A[1][i][j] = s1; A[2][i][j] = s2; A[3][i][j] = s3;
  }
  __syncthreads();

  // wire-factorized basis transform: a=0: .5(X00+X11); a=1: .5(X00-X11); a=2: .5(X01+X10)
  {  // wire 0
    const int w = tid >> 6, ip = (tid >> 3) & 7, jp = tid & 7;
    const float a00 = A[w][ip][jp],     a11 = A[w][ip + 8][jp + 8];
    const float a01 = A[w][ip][jp + 8], a10 = A[w][ip + 8][jp];
    B0[w][0][ip][jp] = 0.5f * (a00 + a11);
    B0[w][1][ip][jp] = 0.5f * (a00 - a11);
    B0[w][2][ip][jp] = 0.5f * (a01 + a10);
  }
  __syncthreads();
  if (tid < 192) {  // wire 1
    const int w = tid / 48, a0 = (tid / 16) % 3, ii = (tid >> 2) & 3, jj = tid & 3;
    const float a00 = B0[w][a0][ii][jj],     a11 = B0[w][a0][ii + 4][jj + 4];
    const float a01 = B0[w][a0][ii][jj + 4], a10 = B0[w][a0][ii + 4][jj];
    B1[w][a0][0][ii][jj] = 0.5f * (a00 + a11);
    B1[w][a0][1][ii][jj] = 0.5f * (a00 - a11);
    B1[w][a0][2][ii][jj] = 0.5f * (a01 + a10);
  }
  __syncthreads();
  if (tid < 144) {  // wire 2
    const int w = tid / 36, a0 = (tid / 12) % 3, a1 = (tid / 4) % 3;
    const int i3 = (tid >> 1) & 1, j3 = tid & 1;
    const float a00 = B1[w][a0][a1][i3][j3],     a11 = B1[w][a0][a1][i3 + 2][j3 + 2];
    const float a01 = B1[w][a0][a1][i3][j3 + 2], a10 = B1[w][a0][a1][i3 + 2][j3];
    B2[w][a0][a1][0][i3][j3] = 0.5f * (a00 + a11);
    B2[w][a0][a1][1][i3][j3] = 0.5f * (a00 - a11);
    B2[w][a0][a1][2][i3][j3] = 0.5f * (a01 + a10);
  }
  __syncthreads();
  if (tid < 108) {  // wire 3 -> C
    const int w = tid / 27, r = tid % 27;
    const int a0 = r / 9, a1 = (r / 3) % 3, a2 = r % 3;
    const float a00 = B2[w][a0][a1][a2][0][0], a11 = B2[w][a0][a1][a2][1][1];
    const float a01 = B2[w][a0][a1][a2][0][1], a10 = B2[w][a0][a1][a2][1][0];
    const int base = (3 * a0 + a1) * 9 + 3 * a2;
    C[(base + 0) * 4 + w] = 0.5f * (a00 + a11);
    C[(base + 1) * 4 + w] = 0.5f * (a00 - a11);
    C[(base + 2) * 4 + w] = 0.5f * (a01 + a10);
  }
}

// ---- main: 1 image/block, 1 patch/thread (low VGPR), early x loads,
// full-wave butterfly reduction, wave-0-redundant softmax. 2 barriers.
__global__ __launch_bounds__(256, 5) void quanv_main(const float* __restrict__ x,
                                                     const float* __restrict__ W,
                                                     const float* __restrict__ bias,
                                                     const float* __restrict__ C,
                                                     float* __restrict__ out,
                                                     int B) {
  __shared__ float4 Cl[81];
  __shared__ float wsum[4][10];
  const int tid = threadIdx.x;
  const int b = blockIdx.x;

  // issue x loads FIRST (clamped patch index keeps threads 196..255 in-bounds)
  const int p = (tid < NPATCH) ? tid : (NPATCH - 1);
  const int pi = p / 14, pj = p - pi * 14;
  const float* px = x + b * 784 + pi * 56 + pj * 2;
  const float2 r0 = *reinterpret_cast<const float2*>(px);
  const float2 r1 = *reinterpret_cast<const float2*>(px + 28);

  if (tid < 81) Cl[tid] = reinterpret_cast<const float4*>(C)[tid];
  __syncthreads();

  float lg[10];
#pragma unroll
  for (int k = 0; k < 10; ++k) lg[k] = 0.0f;

  if (tid < NPATCH) {
    float c0, s0, c1, s1, c2, s2, c3, s3;
    __sincosf(r0.x, &s0, &c0);
    __sincosf(r0.y, &s1, &c1);
    __sincosf(r1.x, &s2, &c2);
    __sincosf(r1.y, &s3, &c3);
    const float m01s[9] = {1.0f, c1, s1, c0, c0 * c1, c0 * s1, s0, s0 * c1, s0 * s1};
    const float m23s[9] = {1.0f, c3, s3, c2, c2 * c3, c2 * s3, s2, s2 * c3, s2 * s3};
    f2 m23b[9];
#pragma unroll
    for (int q = 0; q < 9; ++q) m23b[q] = (f2){m23s[q], m23s[q]};

    f2 f01 = {0.0f, 0.0f}, f23 = {0.0f, 0.0f};
#pragma unroll
    for (int a = 0; a < 9; ++a) {
      f2 t01 = {0.0f, 0.0f}, t23 = {0.0f, 0.0f};
#pragma unroll
      for (int q = 0; q < 9; ++q) {
        const float4 cc = Cl[a * 9 + q];     // wave-uniform LDS broadcast
        t01 += (f2){cc.x, cc.y} * m23b[q];   // v_pk_fma_f32
        t23 += (f2){cc.z, cc.w} * m23b[q];
      }
      f01 += t01 * m01s[a];
      f23 += t23 * m01s[a];
    }

    const float* Wp = W + tid * 4;  // feature index = tid*4 + w
#pragma unroll
    for (int k = 0; k < 10; ++k) {
      const float4 wv = *reinterpret_cast<const float4*>(Wp + k * 784);
      lg[k] = f01.x * wv.x + f01.y * wv.y + f23.x * wv.z + f23.y * wv.w;
    }
  }

  // full 64-lane butterfly; lane 0 of each wave holds the wave total
#pragma unroll
  for (int k = 0; k < 10; ++k) {
    float v = lg[k];
    v += __shfl_xor(v, 1);
    v += __shfl_xor(v, 2);
    v += __shfl_xor(v, 4);
    v += __shfl_xor(v, 8);
    v += __shfl_xor(v, 16);
    v += __shfl_xor(v, 32);
    lg[k] = v;
  }
  if ((tid & 63) == 0) {
    const int wid = tid >> 6;
#pragma unroll
    for (int k = 0; k < 10; ++k) wsum[wid][k] = lg[k];
  }
  __syncthreads();

  // wave 0: every lane redundantly computes all 10 logits + log-softmax
  if (tid < 64) {
    float lgt[10];
    float m = -1e30f;
#pragma unroll
    for (int k = 0; k < 10; ++k) {
      lgt[k] = wsum[0][k] + wsum[1][k] + wsum[2][k] + wsum[3][k] + bias[k];
      m = fmaxf(m, lgt[k]);
    }
    float se = 0.0f;
#pragma unroll
    for (int k = 0; k < 10; ++k) se += expf(lgt[k] - m);
    const float sn = m + logf(se);
    if (tid < 10) out[b * 10 + tid] = lgt[tid] - sn;
  }
}

extern "C" void kernel_launch(void* const* d_in, const int* in_sizes, int n_in,
                              void* d_out, int out_size, void* d_ws, size_t ws_size,
                              hipStream_t stream) {
  const float* x = (const float*)d_in[0];     // (B,1,28,28) f32
  const float* P = (const float*)d_in[1];     // (2,4,3) f32
  const float* W = (const float*)d_in[2];     // (10,784) f32
  const float* bias = (const float*)d_in[3];  // (10,) f32
  float* out = (float*)d_out;                 // (B,10) f32
  float* C = (float*)d_ws;                    // 324 floats scratch
  const int B = out_size / 10;

  quanv_setup<<<1, 256, 0, stream>>>(P, C);
  quanv_main<<<B, 256, 0, stream>>>(x, W, bias, C, out, B);
}

// Round 10
// 24.960 us; speedup vs baseline: 1.7901x; 1.3236x over previous
//
#include <hip/hip_runtime.h>
#include <hip/hip_bf16.h>

#define NPATCH 196

typedef float f2 __attribute__((ext_vector_type(2)));

// ---- setup: ONE block, 256 threads (verbatim, verified absmax 0.0).
// Computes C[(a*9+q)*4+w] so that feat_w = sum_{a,q} C[(a*9+q)*4+w]*m01[a]*m23[q],
// a = 3*alpha0+alpha1 (wires 0,1), q = 3*alpha2+alpha3 (wires 2,3),
// alpha: 0->1, 1->cos(angle), 2->sin(angle).
__global__ __launch_bounds__(256) void quanv_setup(const float* __restrict__ P,
                                                   float* __restrict__ C) {
  __shared__ float gc[24], gs[24];
  __shared__ float Ur[8][2][2], Ui[8][2][2];  // merged RZ*RY*RX per (d,w)
  __shared__ float Sr[2][16][16], Si[2][16][16];
  __shared__ float A[4][16][16];
  __shared__ float B0[4][3][8][8];
  __shared__ float B1[4][3][3][4][4];
  __shared__ float B2[4][3][3][3][2][2];
  const int tid = threadIdx.x;
  const int row = tid >> 4, col = tid & 15;

  if (tid < 24) {  // P laid out [(d*4+w)*3+g]
    float s, c;
    __sincosf(0.5f * P[tid], &s, &c);
    gc[tid] = c; gs[tid] = s;
  }
  Sr[0][row][col] = (row == col) ? 1.0f : 0.0f;
  Si[0][row][col] = 0.0f;
  __syncthreads();

  if (tid < 8) {  // U = RZ(t3)*RY(t2)*RX(t1), 2x2 complex
    const int base = tid * 3;
    const float c1 = gc[base], s1 = gs[base];
    const float c2 = gc[base + 1], s2 = gs[base + 1];
    const float c3 = gc[base + 2], s3 = gs[base + 2];
    const float m00r = c2 * c1, m00i = s2 * s1;
    const float m01r = -s2 * c1, m01i = -c2 * s1;
    const float m10r = s2 * c1, m10i = -c2 * s1;
    const float m11r = c2 * c1, m11i = -s2 * s1;
    Ur[tid][0][0] = c3 * m00r + s3 * m00i;  Ui[tid][0][0] = c3 * m00i - s3 * m00r;
    Ur[tid][0][1] = c3 * m01r + s3 * m01i;  Ui[tid][0][1] = c3 * m01i - s3 * m01r;
    Ur[tid][1][0] = c3 * m10r - s3 * m10i;  Ui[tid][1][0] = c3 * m10i + s3 * m10r;
    Ur[tid][1][1] = c3 * m11r - s3 * m11i;  Ui[tid][1][1] = c3 * m11i + s3 * m11r;
  }
  __syncthreads();

  int cur = 0;
  for (int d = 0; d < 2; ++d) {
    for (int w = 0; w < 4; ++w) {
      const int gi = d * 4 + w;
      const int m = 8 >> w;
      const int bit = (row & m) ? 1 : 0;
      const int par = row ^ m;
      const int r0 = bit ? par : row, r1 = bit ? row : par;
      const float a_r = Sr[cur][r0][col], a_i = Si[cur][r0][col];
      const float b_r = Sr[cur][r1][col], b_i = Si[cur][r1][col];
      const float u0r = Ur[gi][bit][0], u0i = Ui[gi][bit][0];
      const float u1r = Ur[gi][bit][1], u1i = Ui[gi][bit][1];
      const float rn = u0r * a_r - u0i * a_i + u1r * b_r - u1i * b_i;
      const float in_ = u0r * a_i + u0i * a_r + u1r * b_i + u1i * b_r;
      Sr[cur ^ 1][row][col] = rn;
      Si[cur ^ 1][row][col] = in_;
      cur ^= 1;
      __syncthreads();
    }
    if (d == 0) {  // CNOT ring as one permutation: new[k] = old[chain(k)]
      int k = row;
      k ^= (k & 1) ? 8 : 0;
      k ^= (k & 2) ? 1 : 0;
      k ^= (k & 4) ? 2 : 0;
      k ^= (k & 8) ? 4 : 0;
      const float pr_ = Sr[cur][k][col], pi_ = Si[cur][k][col];
      Sr[cur ^ 1][row][col] = pr_;
      Si[cur ^ 1][row][col] = pi_;
      cur ^= 1;
      __syncthreads();
    }
  }

  {  // A_w[i][j]; second CNOT perm folded into row index
    const int i = row, j = col;
    float s0 = 0, s1 = 0, s2 = 0, s3 = 0;
#pragma unroll
    for (int k = 0; k < 16; ++k) {
      int gk = k;
      gk ^= (gk & 1) ? 8 : 0;
      gk ^= (gk & 2) ? 1 : 0;
      gk ^= (gk & 4) ? 2 : 0;
      gk ^= (gk & 8) ? 4 : 0;
      const float pr = Sr[cur][gk][i] * Sr[cur][gk][j] + Si[cur][gk][i] * Si[cur][gk][j];
      s0 += (k & 8) ? -pr : pr;
      s1 += (k & 4) ? -pr : pr;
      s2 += (k & 2) ? -pr : pr;
      s3 += (k & 1) ? -pr : pr;
    }
    A[0][i][j] = s0; A[1][i][j] = s1; A[2][i][j] = s2; A[3][i][j] = s3;
  }
  __syncthreads();

  // wire-factorized basis transform: a=0: .5(X00+X11); a=1: .5(X00-X11); a=2: .5(X01+X10)
  {  // wire 0
    const int w = tid >> 6, ip = (tid >> 3) & 7, jp = tid & 7;
    const float a00 = A[w][ip][jp],     a11 = A[w][ip + 8][jp + 8];
    const float a01 = A[w][ip][jp + 8], a10 = A[w][ip + 8][jp];
    B0[w][0][ip][jp] = 0.5f * (a00 + a11);
    B0[w][1][ip][jp] = 0.5f * (a00 - a11);
    B0[w][2][ip][jp] = 0.5f * (a01 + a10);
  }
  __syncthreads();
  if (tid < 192) {  // wire 1
    const int w = tid / 48, a0 = (tid / 16) % 3, ii = (tid >> 2) & 3, jj = tid & 3;
    const float a00 = B0[w][a0][ii][jj],     a11 = B0[w][a0][ii + 4][jj + 4];
    const float a01 = B0[w][a0][ii][jj + 4], a10 = B0[w][a0][ii + 4][jj];
    B1[w][a0][0][ii][jj] = 0.5f * (a00 + a11);
    B1[w][a0][1][ii][jj] = 0.5f * (a00 - a11);
    B1[w][a0][2][ii][jj] = 0.5f * (a01 + a10);
  }
  __syncthreads();
  if (tid < 144) {  // wire 2
    const int w = tid / 36, a0 = (tid / 12) % 3, a1 = (tid / 4) % 3;
    const int i3 = (tid >> 1) & 1, j3 = tid & 1;
    const float a00 = B1[w][a0][a1][i3][j3],     a11 = B1[w][a0][a1][i3 + 2][j3 + 2];
    const float a01 = B1[w][a0][a1][i3][j3 + 2], a10 = B1[w][a0][a1][i3 + 2][j3];
    B2[w][a0][a1][0][i3][j3] = 0.5f * (a00 + a11);
    B2[w][a0][a1][1][i3][j3] = 0.5f * (a00 - a11);
    B2[w][a0][a1][2][i3][j3] = 0.5f * (a01 + a10);
  }
  __syncthreads();
  if (tid < 108) {  // wire 3 -> C
    const int w = tid / 27, r = tid % 27;
    const int a0 = r / 9, a1 = (r / 3) % 3, a2 = r % 3;
    const float a00 = B2[w][a0][a1][a2][0][0], a11 = B2[w][a0][a1][a2][1][1];
    const float a01 = B2[w][a0][a1][a2][0][1], a10 = B2[w][a0][a1][a2][1][0];
    const int base = (3 * a0 + a1) * 9 + 3 * a2;
    C[(base + 0) * 4 + w] = 0.5f * (a00 + a11);
    C[(base + 1) * 4 + w] = 0.5f * (a00 - a11);
    C[(base + 2) * 4 + w] = 0.5f * (a01 + a10);
  }
}

// ---- main: ONE WAVE PER IMAGE, 4 waves/block -> grid B/4 = 1024 blocks
// = 4 blocks/CU = ALL images resident. W staged in LDS (shared by 4 waves);
// C read from global with wave-uniform indices -> scalar s_load path.
// One barrier total; in-wave butterfly; redundant in-register softmax.
__global__ __launch_bounds__(256, 4) void quanv_main(const float* __restrict__ x,
                                                     const float* __restrict__ W,
                                                     const float* __restrict__ bias,
                                                     const float* __restrict__ C,
                                                     float* __restrict__ out,
                                                     int B) {
  __shared__ float4 Wl[1960];  // Wl[k*196 + p] = W[k*784 + 4p .. 4p+3]
  const int tid = threadIdx.x;

  const float4* Wg = reinterpret_cast<const float4*>(W);
  for (int i = tid; i < 1960; i += 256) Wl[i] = Wg[i];
  __syncthreads();

  const int wid = tid >> 6, lane = tid & 63;
  const int b = blockIdx.x * 4 + wid;
  if (b >= B) return;

  const float* xb = x + b * 784;
  const float4* C4 = reinterpret_cast<const float4*>(C);  // uniform -> s_load

  float lg[10];
#pragma unroll
  for (int k = 0; k < 10; ++k) lg[k] = 0.0f;

#pragma unroll 1
  for (int t = 0; t < 4; ++t) {
    const int p = lane + 64 * t;
    if (p < NPATCH) {
      const int pi = p / 14, pj = p - pi * 14;
      const float* px = xb + pi * 56 + pj * 2;
      const float2 r0 = *reinterpret_cast<const float2*>(px);
      const float2 r1 = *reinterpret_cast<const float2*>(px + 28);
      float c0, s0, c1, s1, c2, s2, c3, s3;
      __sincosf(r0.x, &s0, &c0);
      __sincosf(r0.y, &s1, &c1);
      __sincosf(r1.x, &s2, &c2);
      __sincosf(r1.y, &s3, &c3);
      const float m01s[9] = {1.0f, c1, s1, c0, c0 * c1, c0 * s1, s0, s0 * c1, s0 * s1};
      const float m23s[9] = {1.0f, c3, s3, c2, c2 * c3, c2 * s3, s2, s2 * c3, s2 * s3};
      f2 m23b[9];
#pragma unroll
      for (int q = 0; q < 9; ++q) m23b[q] = (f2){m23s[q], m23s[q]};

      f2 f01 = {0.0f, 0.0f}, f23 = {0.0f, 0.0f};
#pragma unroll
      for (int a = 0; a < 9; ++a) {
        f2 t01 = {0.0f, 0.0f}, t23 = {0.0f, 0.0f};
#pragma unroll
        for (int q = 0; q < 9; ++q) {
          const float4 cc = C4[a * 9 + q];     // wave-uniform global -> s_load
          t01 += (f2){cc.x, cc.y} * m23b[q];   // v_pk_fma_f32 (SGPR operand)
          t23 += (f2){cc.z, cc.w} * m23b[q];
        }
        f01 += t01 * m01s[a];
        f23 += t23 * m01s[a];
      }

#pragma unroll
      for (int k = 0; k < 10; ++k) {
        const float4 wv = Wl[k * 196 + p];     // coalesced ds_read_b128
        lg[k] += f01.x * wv.x + f01.y * wv.y + f23.x * wv.z + f23.y * wv.w;
      }
    }
  }

  // full 64-lane butterfly: every lane ends with the image totals
#pragma unroll
  for (int k = 0; k < 10; ++k) {
    float v = lg[k];
    v += __shfl_xor(v, 1);
    v += __shfl_xor(v, 2);
    v += __shfl_xor(v, 4);
    v += __shfl_xor(v, 8);
    v += __shfl_xor(v, 16);
    v += __shfl_xor(v, 32);
    lg[k] = v + bias[k];
  }

  // redundant in-register log-softmax
  float m = lg[0];
#pragma unroll
  for (int k = 1; k < 10; ++k) m = fmaxf(m, lg[k]);
  float se = 0.0f;
#pragma unroll
  for (int k = 0; k < 10; ++k) se += expf(lg[k] - m);
  const float sn = m + logf(se);

  if (lane < 10) {
    float v = lg[0];
#pragma unroll
    for (int k = 1; k < 10; ++k) v = (lane == k) ? lg[k] : v;
    out[b * 10 + lane] = v - sn;
  }
}

extern "C" void kernel_launch(void* const* d_in, const int* in_sizes, int n_in,
                              void* d_out, int out_size, void* d_ws, size_t ws_size,
                              hipStream_t stream) {
  const float* x = (const float*)d_in[0];     // (B,1,28,28) f32
  const float* P = (const float*)d_in[1];     // (2,4,3) f32
  const float* W = (const float*)d_in[2];     // (10,784) f32
  const float* bias = (const float*)d_in[3];  // (10,) f32
  float* out = (float*)d_out;                 // (B,10) f32
  float* C = (float*)d_ws;                    // 324 floats scratch
  const int B = out_size / 10;

  quanv_setup<<<1, 256, 0, stream>>>(P, C);
  quanv_main<<<(B + 3) / 4, 256, 0, stream>>>(x, W, bias, C, out, B);
}